// Round 4
// baseline (538.574 us; speedup 1.0000x reference)
//
#include <hip/hip_runtime.h>

#define B_TOT   4096
#define T_STEPS 512
#define IN_F    5
#define D_FC    32
#define D_H     64
#define MB      4       // batches per block; batch b lives at M-tile row 4b (= quad)
#define NROW    16      // MFMA M-tile rows staged in LDS
#define ROWE    72      // f16 elems per row (64 h + 8 pad; 144B rows stay 16B-aligned)

typedef _Float16 h8 __attribute__((ext_vector_type(8)));
typedef float    f4 __attribute__((ext_vector_type(4)));

__device__ __forceinline__ float fexp2(float x) { return __builtin_amdgcn_exp2f(x); }
__device__ __forceinline__ float frcp(float x)  { return __builtin_amdgcn_rcpf(x); }

__global__ __launch_bounds__(256, 4) void lstm_mfma(
    const float* __restrict__ x,
    const float* __restrict__ W0,
    const float* __restrict__ b0,
    const float* __restrict__ W_ih,
    const float* __restrict__ W_hh,
    const float* __restrict__ b_ih,
    const float* __restrict__ b_hh,
    const float* __restrict__ Wo,
    const float* __restrict__ bo,
    float* __restrict__ out)
{
    // double-buffered h(t-1), f16
    __shared__ __align__(16) _Float16 H[2][NROW][ROWE];

    const int tid  = threadIdx.x;
    const int lane = tid & 63;
    const int w    = tid >> 6;      // wave id: owns hidden j in [w*16, w*16+16)
    const int col  = lane & 15;
    const int quad = lane >> 4;     // = batch owned by this lane's acc row (quad*4)
    const int bblk = blockIdx.x * MB;

    const float K1 = 1.4426950408889634f;   // log2(e)
    const float K2 = 2.8853900817779268f;   // 2*log2(e)

    // ---- resident W_hh B-fragments (8 MFMAs/step use these) ----
    h8 Bf[4][2];
    #pragma unroll
    for (int q = 0; q < 4; ++q) {
        const int row = q * 64 + w * 16 + col;
        #pragma unroll
        for (int c = 0; c < 2; ++c) {
            h8 f;
            #pragma unroll
            for (int jj = 0; jj < 8; ++jj) {
                const int k = c * 32 + quad * 8 + jj;
                f[jj] = (_Float16)W_hh[row * D_H + k];
            }
            Bf[q][c] = f;
        }
    }

    // ---- folded x-side weights, lane-private f32: Weff[q] = (W_ih * W0)[row], k=0..4 ----
    float Wx[4][IN_F];
    #pragma unroll
    for (int q = 0; q < 4; ++q) {
        const int row = q * 64 + w * 16 + col;
        #pragma unroll
        for (int jj = 0; jj < IN_F; ++jj) {
            float s = 0.0f;
            #pragma unroll
            for (int m = 0; m < D_FC; ++m)
                s = fmaf(W_ih[row * D_FC + m], W0[m * IN_F + jj], s);
            Wx[q][jj] = s;
        }
    }

    // ---- folded bias, pre-scaled into the exp2 argument ----
    float sb[4];
    #pragma unroll
    for (int q = 0; q < 4; ++q) {
        const int row = q * 64 + w * 16 + col;
        float s = b_ih[row] + b_hh[row];
        #pragma unroll
        for (int m = 0; m < D_FC; ++m)
            s = fmaf(W_ih[row * D_FC + m], b0[m], s);
        sb[q] = s;
    }
    const float nbi = -K1 * sb[0];
    const float nbf = -K1 * sb[1];
    const float pbg =  K2 * sb[2];
    const float nbo = -K1 * sb[3];

    // ---- zero both LDS buffers (h(-1)=0; garbage rows stay 0 forever) ----
    for (int i = tid; i < 2 * NROW * ROWE; i += 256)
        ((_Float16*)H)[i] = (_Float16)0.0f;

    // ---- x feed: lane consumes x of its own batch (= quad) ----
    const float* xb = x + (size_t)(bblk + quad) * T_STEPS * IN_F;

    union X5 { struct { f4 v; float s; } p; float e[5]; };
    X5 xe, xo;                       // x(even t), x(odd t)
    xe.p.v = *(const f4*)xb;          xe.p.s = xb[4];               // x(0)
    xo.p.v = *(const f4*)(xb + IN_F); xo.p.s = xb[IN_F + 4];        // x(1)

    f4 zk = {0.0f, 0.0f, 0.0f, 0.0f};
    float cs = 0.0f;   // cell state: lane owns (batch=quad, j=w*16+col)

    __syncthreads();    // zero-init visible

    for (int it = 0; it < T_STEPS / 2; ++it) {
        #pragma unroll
        for (int u = 0; u < 2; ++u) {
            // h(t-1) A-fragments from buffer u
            const h8 A1 = *(const h8*)&H[u][col][quad * 8];
            const h8 A2 = *(const h8*)&H[u][col][32 + quad * 8];

            // x-side gate contribution on VALU (fills ds_read latency):
            // xg_q = Weff[q] . x_t ; merged into the trans-arg constants
            const float* xc = (u == 0) ? xe.e : xo.e;
            float xg[4];
            #pragma unroll
            for (int q = 0; q < 4; ++q) {
                float s = Wx[q][0] * xc[0];
                #pragma unroll
                for (int k = 1; k < IN_F; ++k) s = fmaf(Wx[q][k], xc[k], s);
                xg[q] = s;
            }
            const float dbi = fmaf(-K1, xg[0], nbi);
            const float dbf = fmaf(-K1, xg[1], nbf);
            const float dbg = fmaf( K2, xg[2], pbg);
            const float dbo = fmaf(-K1, xg[3], nbo);

            // reload this parity's x with x(t+2); stays in flight across barriers
            {
                int tn = 2 * it + u + 2;
                tn = (tn < T_STEPS) ? tn : (T_STEPS - 1);
                const float* xp = xb + tn * IN_F;
                if (u == 0) { xe.p.v = *(const f4*)xp; xe.p.s = xp[4]; }
                else        { xo.p.v = *(const f4*)xp; xo.p.s = xp[4]; }
            }

            // h-side MFMAs (8 per wave-step)
            f4 acc[4];
            #pragma unroll
            for (int q = 0; q < 4; ++q) {
                f4 a = __builtin_amdgcn_mfma_f32_16x16x32_f16(A2, Bf[q][1], zk, 0, 0, 0);
                a = __builtin_amdgcn_mfma_f32_16x16x32_f16(A1, Bf[q][0], a, 0, 0, 0);
                acc[q] = a;
            }

            // elementwise LSTM: lane owns exactly one element (batch=quad, reg 0)
            {
                const float ig = frcp(1.0f + fexp2(fmaf(-K1, acc[0][0], dbi)));
                const float fg = frcp(1.0f + fexp2(fmaf(-K1, acc[1][0], dbf)));
                const float eg = fexp2(fmaf(K2, acc[2][0], dbg));
                const float gg = fmaf(-2.0f, frcp(eg + 1.0f), 1.0f);
                const float og = frcp(1.0f + fexp2(fmaf(-K1, acc[3][0], dbo)));
                cs = fmaf(fg, cs, ig * gg);
                const float ec = fexp2(K2 * cs);
                const float th = fmaf(-2.0f, frcp(ec + 1.0f), 1.0f);
                H[u ^ 1][quad * 4][w * 16 + col] = (_Float16)(og * th);
            }

            // barrier WITHOUT vmcnt(0) drain: LDS writes visible, x-prefetch in flight
            asm volatile("s_waitcnt lgkmcnt(0)" ::: "memory");
            __builtin_amdgcn_s_barrier();
            asm volatile("" ::: "memory");
        }
    }

    // ---- output head: h_last lives in H[0]; batch b at row 4b ----
    if (tid < MB) {
        const int hr = tid * 4;
        float a = bo[0];
        #pragma unroll 8
        for (int j = 0; j < D_H; ++j)
            a = fmaf((float)H[0][hr][j], Wo[j], a);
        out[bblk + tid] = a;
    }
}

extern "C" void kernel_launch(void* const* d_in, const int* in_sizes, int n_in,
                              void* d_out, int out_size, void* d_ws, size_t ws_size,
                              hipStream_t stream) {
    const float* x    = (const float*)d_in[0];
    const float* W0   = (const float*)d_in[1];
    const float* b0   = (const float*)d_in[2];
    const float* W_ih = (const float*)d_in[3];
    const float* W_hh = (const float*)d_in[4];
    const float* b_ih = (const float*)d_in[5];
    const float* b_hh = (const float*)d_in[6];
    const float* Wo   = (const float*)d_in[7];
    const float* bo   = (const float*)d_in[8];
    float* out = (float*)d_out;

    hipLaunchKernelGGL(lstm_mfma, dim3(B_TOT / MB), dim3(256), 0, stream,
                       x, W0, b0, W_ih, W_hh, b_ih, b_hh, Wo, bo, out);
}

// Round 5
// 328.443 us; speedup vs baseline: 1.6398x; 1.6398x over previous
//
#include <hip/hip_runtime.h>

#define B_TOT   4096
#define T_STEPS 512
#define IN_F    5
#define D_FC    32
#define D_H     64
#define MB      16      // batches per block; DENSE M-tile: batch b = A-row b
#define NROW    16      // MFMA M-tile rows staged in LDS
#define ROWE    72      // f16 elems per row (64 h + 8 pad; 144B rows stay 16B-aligned)

typedef _Float16 h8 __attribute__((ext_vector_type(8)));
typedef __fp16   h2 __attribute__((ext_vector_type(2)));
typedef float    f4 __attribute__((ext_vector_type(4)));

__device__ __forceinline__ float fexp2(float x) { return __builtin_amdgcn_exp2f(x); }
__device__ __forceinline__ float frcp(float x)  { return __builtin_amdgcn_rcpf(x); }

__global__ __launch_bounds__(256) void lstm_mfma(
    const float* __restrict__ x,
    const float* __restrict__ W0,
    const float* __restrict__ b0,
    const float* __restrict__ W_ih,
    const float* __restrict__ W_hh,
    const float* __restrict__ b_ih,
    const float* __restrict__ b_hh,
    const float* __restrict__ Wo,
    const float* __restrict__ bo,
    float* __restrict__ out)
{
    // double-buffered h(t-1), f16: H[buf][batch-row][hidden]
    __shared__ __align__(16) _Float16 H[2][NROW][ROWE];

    const int tid  = threadIdx.x;
    const int lane = tid & 63;
    const int w    = tid >> 6;      // wave id: owns hidden j in [w*16, w*16+16)
    const int col  = lane & 15;
    const int quad = lane >> 4;
    const int bblk = blockIdx.x * MB;

    const float K1 = 1.4426950408889634f;   // log2(e)
    const float K2 = 2.8853900817779268f;   // 2*log2(e)

    // ---- resident W_hh B-fragments: gate q, j = w*16+col, K = hidden 0..63 ----
    h8 Bf[4][2];
    #pragma unroll
    for (int q = 0; q < 4; ++q) {
        const int row = q * 64 + w * 16 + col;
        #pragma unroll
        for (int c = 0; c < 2; ++c) {
            h8 f;
            #pragma unroll
            for (int jj = 0; jj < 8; ++jj) {
                const int k = c * 32 + quad * 8 + jj;
                f[jj] = (_Float16)W_hh[row * D_H + k];
            }
            Bf[q][c] = f;
        }
    }

    // ---- folded x-side weights: Weff = W_ih * W0 (256 x 5), K=32-padded frag ----
    h8 Bx[4];
    #pragma unroll
    for (int q = 0; q < 4; ++q) {
        const int row = q * 64 + w * 16 + col;
        h8 f;
        #pragma unroll
        for (int jj = 0; jj < 8; ++jj) f[jj] = (_Float16)0.0f;
        if (quad == 0) {
            #pragma unroll
            for (int jj = 0; jj < IN_F; ++jj) {
                float s = 0.0f;
                #pragma unroll
                for (int m = 0; m < D_FC; ++m)
                    s = fmaf(W_ih[row * D_FC + m], W0[m * IN_F + jj], s);
                f[jj] = (_Float16)s;
            }
        }
        Bx[q] = f;
    }

    // ---- folded bias, pre-scaled into the exp2 argument ----
    float sb[4];
    #pragma unroll
    for (int q = 0; q < 4; ++q) {
        const int row = q * 64 + w * 16 + col;
        float s = b_ih[row] + b_hh[row];
        #pragma unroll
        for (int m = 0; m < D_FC; ++m)
            s = fmaf(W_ih[row * D_FC + m], b0[m], s);
        sb[q] = s;
    }
    const float nbi = -K1 * sb[0];
    const float nbf = -K1 * sb[1];
    const float pbg =  K2 * sb[2];
    const float nbo = -K1 * sb[3];

    // ---- zero both LDS buffers (h(-1)=0) ----
    for (int i = tid; i < 2 * NROW * ROWE; i += 256)
        ((_Float16*)H)[i] = (_Float16)0.0f;

    // ---- x feed: A-frag row = batch = col (all quads duplicate the load) ----
    const float* xb = x + (size_t)(bblk + col) * T_STEPS * IN_F;

    union AxU { h8 v; h2 p[4]; };
    AxU Ax[2];
    #pragma unroll
    for (int jj = 0; jj < 8; ++jj) { Ax[0].v[jj] = (_Float16)0.0f; Ax[1].v[jj] = (_Float16)0.0f; }
    {   // Ax[0] = x(0)
        const f4 v0 = *(const f4*)xb;
        const float s0 = xb[4];
        Ax[0].p[0] = __builtin_amdgcn_cvt_pkrtz(v0[0], v0[1]);
        Ax[0].p[1] = __builtin_amdgcn_cvt_pkrtz(v0[2], v0[3]);
        Ax[0].p[2] = __builtin_amdgcn_cvt_pkrtz(s0, 0.0f);
    }
    // prefetch buffers: xv[0]=x(1), xv[1]=x(2)
    f4 xv[2]; float x4[2];
    xv[0] = *(const f4*)(xb + IN_F);      x4[0] = xb[IN_F + 4];
    xv[1] = *(const f4*)(xb + 2 * IN_F);  x4[1] = xb[2 * IN_F + 4];

    f4 zk = {0.0f, 0.0f, 0.0f, 0.0f};
    // cell state: lane owns (batch = quad*4+r, j = w*16+col), r = 0..3
    float cs[4] = {0.0f, 0.0f, 0.0f, 0.0f};

    __syncthreads();    // zero-init visible

    for (int it = 0; it < T_STEPS / 2; ++it) {
        #pragma unroll
        for (int u = 0; u < 2; ++u) {
            // h(t-1) A-fragments from buffer u
            const h8 A1 = *(const h8*)&H[u][col][quad * 8];
            const h8 A2 = *(const h8*)&H[u][col][32 + quad * 8];

            // pack next-step Ax while lgkm pending; then issue x(t+3) prefetch
            Ax[u ^ 1].p[0] = __builtin_amdgcn_cvt_pkrtz(xv[u][0], xv[u][1]);
            Ax[u ^ 1].p[1] = __builtin_amdgcn_cvt_pkrtz(xv[u][2], xv[u][3]);
            Ax[u ^ 1].p[2] = __builtin_amdgcn_cvt_pkrtz(x4[u], 0.0f);
            {
                int tn = 2 * it + u + 3;
                tn = (tn < T_STEPS) ? tn : (T_STEPS - 1);
                const float* xp = xb + tn * IN_F;
                xv[u] = *(const f4*)xp;     // stays in flight across barriers
                x4[u] = xp[4];
            }

            // 12 MFMAs: x-MFMA first (register operands — issues during ds_read wait)
            f4 acc[4];
            #pragma unroll
            for (int q = 0; q < 4; ++q) {
                f4 a = __builtin_amdgcn_mfma_f32_16x16x32_f16(Ax[u].v, Bx[q], zk, 0, 0, 0);
                a = __builtin_amdgcn_mfma_f32_16x16x32_f16(A1, Bf[q][0], a, 0, 0, 0);
                a = __builtin_amdgcn_mfma_f32_16x16x32_f16(A2, Bf[q][1], a, 0, 0, 0);
                acc[q] = a;
            }

            // elementwise LSTM: lane owns 4 elements (batch = quad*4+r, j = w*16+col)
            #pragma unroll
            for (int r = 0; r < 4; ++r) {
                const float ig = frcp(1.0f + fexp2(fmaf(-K1, acc[0][r], nbi)));
                const float fg = frcp(1.0f + fexp2(fmaf(-K1, acc[1][r], nbf)));
                const float eg = fexp2(fmaf(K2, acc[2][r], pbg));
                const float gg = fmaf(-2.0f, frcp(eg + 1.0f), 1.0f);
                const float og = frcp(1.0f + fexp2(fmaf(-K1, acc[3][r], nbo)));
                cs[r] = fmaf(fg, cs[r], ig * gg);
                const float ec = fexp2(K2 * cs[r]);
                const float th = fmaf(-2.0f, frcp(ec + 1.0f), 1.0f);
                H[u ^ 1][quad * 4 + r][w * 16 + col] = (_Float16)(og * th);
            }

            // barrier WITHOUT vmcnt(0) drain: LDS writes visible, x-prefetch in flight
            asm volatile("s_waitcnt lgkmcnt(0)" ::: "memory");
            __builtin_amdgcn_s_barrier();
            asm volatile("" ::: "memory");
        }
    }

    // ---- output head: h_last lives in H[0]; batch b at row b ----
    if (tid < MB) {
        float a = bo[0];
        #pragma unroll 8
        for (int j = 0; j < D_H; ++j)
            a = fmaf((float)H[0][tid][j], Wo[j], a);
        out[bblk + tid] = a;
    }
}

extern "C" void kernel_launch(void* const* d_in, const int* in_sizes, int n_in,
                              void* d_out, int out_size, void* d_ws, size_t ws_size,
                              hipStream_t stream) {
    const float* x    = (const float*)d_in[0];
    const float* W0   = (const float*)d_in[1];
    const float* b0   = (const float*)d_in[2];
    const float* W_ih = (const float*)d_in[3];
    const float* W_hh = (const float*)d_in[4];
    const float* b_ih = (const float*)d_in[5];
    const float* b_hh = (const float*)d_in[6];
    const float* Wo   = (const float*)d_in[7];
    const float* bo   = (const float*)d_in[8];
    float* out = (float*)d_out;

    hipLaunchKernelGGL(lstm_mfma, dim3(B_TOT / MB), dim3(256), 0, stream,
                       x, W0, b0, W_ih, W_hh, b_ih, b_hh, Wo, bo, out);
}